// Round 12
// baseline (3616.979 us; speedup 1.0000x reference)
//
#include <hip/hip_runtime.h>
#include <stdint.h>

// ---------- common types / helpers ----------
typedef unsigned short u16;
typedef __bf16 v8bf __attribute__((ext_vector_type(8)));
typedef short v8s  __attribute__((ext_vector_type(8)));
typedef float v4f  __attribute__((ext_vector_type(4)));

template <int N> struct IC { static constexpr int value = N; };

__device__ __forceinline__ u16 f2b(float f) {
  unsigned int x = __float_as_uint(f);
  x += 0x7fffu + ((x >> 16) & 1u);   // RNE
  return (u16)(x >> 16);
}
__device__ __forceinline__ float b2f(u16 u) {
  return __uint_as_float(((unsigned int)u) << 16);
}

// async global->LDS, 16B per lane; lds arg = wave-uniform base, HW adds lane*16
__device__ __forceinline__ void gld16(void* lds, const void* g) {
  __builtin_amdgcn_global_load_lds(
      (const __attribute__((address_space(1))) void*)g,
      (__attribute__((address_space(3))) void*)lds, 16, 0, 0);
}

__device__ __forceinline__ v4f mfma16(v8s a, v8s b, v4f c) {
  return __builtin_amdgcn_mfma_f32_16x16x32_bf16(
      __builtin_bit_cast(v8bf, a), __builtin_bit_cast(v8bf, b), c, 0, 0, 0);
}

template <int N>
__device__ __forceinline__ void wait_vm() {
  if constexpr (N == 0) asm volatile("s_waitcnt vmcnt(0)" ::: "memory");
  else if constexpr (N == 4) asm volatile("s_waitcnt vmcnt(4)" ::: "memory");
  else if constexpr (N == 6) asm volatile("s_waitcnt vmcnt(6)" ::: "memory");
  else asm volatile("s_waitcnt vmcnt(8)" ::: "memory");
}
__device__ __forceinline__ void wait_lgkm0() {
  asm volatile("s_waitcnt lgkmcnt(0)" ::: "memory");
}

// conflict-free swizzle for [ROWS][32] bf16 K-tiles (64B rows):
// 16B-granule g (0..3) of row r stored at granule g ^ ((r>>1)&3).
// (verified: SQ_LDS_BANK_CONFLICT == 0)
__device__ __forceinline__ int swz(int r, int g) {
  return r * 32 + ((g ^ ((r >> 1) & 3)) * 8);
}

// XCD-aware chunked block swizzle (helps K=4096 small-N GEMMs; hurts dual/QKVG geometry)
__device__ __forceinline__ void xcd_map(int gx, int gy, int& bx, int& by) {
  const int nwg = gx * gy;
  int lin = blockIdx.y * gx + blockIdx.x;
  const int per = nwg >> 3;
  lin = (lin & 7) * per + (lin >> 3);
  bx = lin % gx;
  by = lin / gx;
}

// ---------- weight transpose+convert: src [K,N] f32 -> dst [N,K] bf16 ----------
struct TransArgs {
  const float* src[10];
  u16* dst[10];
  int K, N;
};
__global__ __launch_bounds__(256) void wtrans(TransArgs p) {
  const float* src = p.src[blockIdx.z];
  u16* dst = p.dst[blockIdx.z];
  __shared__ float t[32][33];
  const int tx = threadIdx.x & 31, ty = threadIdx.x >> 5;
  const int n0 = blockIdx.x * 32, k0 = blockIdx.y * 32;
#pragma unroll
  for (int j = 0; j < 4; j++)
    t[ty * 4 + j][tx] = src[(size_t)(k0 + ty * 4 + j) * p.N + n0 + tx];
  __syncthreads();
#pragma unroll
  for (int j = 0; j < 4; j++)
    dst[(size_t)(n0 + ty * 4 + j) * p.K + k0 + tx] = f2b(t[tx][ty * 4 + j]);
}

// ---------- input projection: block = 32 rows x 128 cols, W amortized 16x ----
__global__ __launch_bounds__(256) void inproj(const float* __restrict__ cgm,
                                              const float* __restrict__ Win,
                                              const float* __restrict__ bin,
                                              float* __restrict__ X,
                                              u16* __restrict__ XB) {
  __shared__ float sc[32][33];
  const int tid = threadIdx.x;
  const int m0 = blockIdx.y * 32, n0 = blockIdx.x * 128;
  for (int i = tid; i < 1024; i += 256)
    sc[i >> 5][i & 31] = cgm[(size_t)(m0 + (i >> 5)) * 32 + (i & 31)];
  __syncthreads();
  const int n = n0 + (tid & 127);
  const int rh = (tid >> 7) * 16;
  float acc[16];
  const float b = bin[n];
#pragma unroll
  for (int r = 0; r < 16; r++) acc[r] = b;
  for (int k = 0; k < 32; k++) {
    const float wv = Win[k * 1024 + n];
#pragma unroll
    for (int r = 0; r < 16; r++) acc[r] = fmaf(sc[rh + r][k], wv, acc[r]);
  }
#pragma unroll
  for (int r = 0; r < 16; r++) {
    const size_t idx = (size_t)(m0 + rh + r) * 1024 + n;
    X[idx] = acc[r];
    XB[idx] = f2b(acc[r]);
  }
}

#define GE_QKVG 0
#define GE_OPROJ 1
#define GE_FF2 2

struct GemmArgs {
  const u16* A;
  const u16* Bt;
  const float *bias0, *bias1, *bias2, *bias3;
  u16 *ob0, *ob1, *ob2, *ob3;
  const float* resF;
  const u16* gate;
  float* outF;
  const float *mean, *rstd, *lnS, *lnB;
  int K, N;
};

// ---------- 8-wave phase-pipelined GEMM: BM=256, BN=256, BK=32, 4 LDS bufs ----
template <int EPI>
__global__ __launch_bounds__(512, 2) void gemm8w(GemmArgs p) {
  __shared__ __align__(16) u16 sA[4][256 * 32];
  __shared__ __align__(16) u16 sB[4][256 * 32];
  const int tid = threadIdx.x, w = tid >> 6, l = tid & 63;
  const int wm = w >> 2, wn = w & 3;   // 2M x 4N waves, per-wave 128x64
  const int m0 = blockIdx.y * 256, n0 = blockIdx.x * 256;
  const int K = p.K, NT = K >> 5;

  v4f acc[8][4];
#pragma unroll
  for (int i = 0; i < 8; i++)
#pragma unroll
    for (int j = 0; j < 4; j++) acc[i][j] = (v4f){0.f, 0.f, 0.f, 0.f};

  int aOff[8], bOff[4];
#pragma unroll
  for (int i = 0; i < 8; i++) aOff[i] = swz(wm * 128 + i * 16 + (l & 15), l >> 4);
#pragma unroll
  for (int i = 0; i < 4; i++) bOff[i] = swz(wn * 64 + i * 16 + (l & 15), l >> 4);

  const int srow = tid >> 2, sg = tid & 3;
  const u16 *gA[2], *gB[2];
#pragma unroll
  for (int j = 0; j < 2; j++) {
    const int r = j * 128 + srow;
    const int co = (sg ^ ((r >> 1) & 3)) * 8;
    gA[j] = p.A + (size_t)(m0 + r) * K + co;
    gB[j] = p.Bt + (size_t)(n0 + r) * K + co;
  }

  // prologue: stage tiles 0,1
#pragma unroll
  for (int b = 0; b < 2; b++) {
#pragma unroll
    for (int j = 0; j < 2; j++) { gld16(&sA[b][j * 4096 + w * 512], gA[j]); gA[j] += 32; }
#pragma unroll
    for (int j = 0; j < 2; j++) { gld16(&sB[b][j * 4096 + w * 512], gB[j]); gB[j] += 32; }
  }
  wait_vm<4>();
  __builtin_amdgcn_s_barrier();

  auto tb = [&](int T, auto rbT) {
    constexpr int RB = decltype(rbT)::value;
    constexpr int SB = (RB + 2) & 3;
    const bool st = (T + 2) < NT;
    // ---- phase 0: B frags + A frags 0-3; stage next A ----
    v8s bf[4], af[4];
#pragma unroll
    for (int i = 0; i < 4; i++) bf[i] = *(const v8s*)&sB[RB][bOff[i]];
#pragma unroll
    for (int i = 0; i < 4; i++) af[i] = *(const v8s*)&sA[RB][aOff[i]];
    if (st) {
#pragma unroll
      for (int j = 0; j < 2; j++) { gld16(&sA[SB][j * 4096 + w * 512], gA[j]); gA[j] += 32; }
    }
    __builtin_amdgcn_s_barrier();
    wait_lgkm0();
    __builtin_amdgcn_s_setprio(1);
#pragma unroll
    for (int mt = 0; mt < 4; mt++)
#pragma unroll
      for (int nt = 0; nt < 4; nt++)
        acc[mt][nt] = mfma16(af[mt], bf[nt], acc[mt][nt]);
    __builtin_amdgcn_s_setprio(0);
    // ---- phase 1: A frags 4-7; stage next B; tile-boundary vmcnt ----
    v8s af1[4];
#pragma unroll
    for (int i = 0; i < 4; i++) af1[i] = *(const v8s*)&sA[RB][aOff[4 + i]];
    if (st) {
#pragma unroll
      for (int j = 0; j < 2; j++) { gld16(&sB[SB][j * 4096 + w * 512], gB[j]); gB[j] += 32; }
      wait_vm<4>();
    } else if (T + 2 == NT) {
      wait_vm<0>();
    }
    __builtin_amdgcn_s_barrier();
    wait_lgkm0();
    __builtin_amdgcn_s_setprio(1);
#pragma unroll
    for (int mt = 0; mt < 4; mt++)
#pragma unroll
      for (int nt = 0; nt < 4; nt++)
        acc[4 + mt][nt] = mfma16(af1[mt], bf[nt], acc[4 + mt][nt]);
    __builtin_amdgcn_s_setprio(0);
  };

  for (int t = 0; t < NT; t += 4) {
    tb(t, IC<0>{});
    tb(t + 1, IC<1>{});
    tb(t + 2, IC<2>{});
    tb(t + 3, IC<3>{});
  }

#pragma unroll
  for (int mt = 0; mt < 8; mt++) {
#pragma unroll
    for (int nt = 0; nt < 4; nt++) {
      const int col = n0 + wn * 64 + nt * 16 + (l & 15);
#pragma unroll
      for (int r = 0; r < 4; r++) {
        const int row = m0 + wm * 128 + mt * 16 + (l >> 4) * 4 + r;
        float v = acc[mt][nt][r];
        if (EPI == GE_QKVG) {
          const int chunk = col >> 10, nl = col & 1023;
          const float* bias = (chunk == 0) ? p.bias0 : (chunk == 1) ? p.bias1
                              : (chunk == 2) ? p.bias2 : p.bias3;
          u16* dst = (chunk == 0) ? p.ob0 : (chunk == 1) ? p.ob1
                     : (chunk == 2) ? p.ob2 : p.ob3;
          v += bias[nl];
          if (chunk == 3) v = 1.f / (1.f + __expf(-v));
          dst[(size_t)row * 1024 + nl] = f2b(v);
        } else if (EPI == GE_OPROJ) {
          v += p.bias0[col];
          const size_t idx = (size_t)row * 1024 + col;
          p.outF[idx] = p.resF[idx] + b2f(p.gate[idx]) * v;
        } else {
          v += p.bias0[col];
          const size_t idx = (size_t)row * 1024 + col;
          const float u = p.resF[idx];
          const float h = (u - p.mean[row]) * p.rstd[row] * p.lnS[col] + p.lnB[col];
          p.outF[idx] = h + v;
        }
      }
    }
  }
}

// ---------- dual GEMM (FF1): m97-exact config — 4 waves, BM=128, BK=32,
// 2 LDS buffers (48KB -> 3 blocks/CU), stage-1-ahead, vmcnt(0) per tile ----
struct DualArgs {
  const u16* A;
  const u16 *B1, *B2;
  const float *bias1, *bias2;
  u16* out;
  int K;
};
__global__ __launch_bounds__(256, 3) void dual2b(DualArgs p) {
  __shared__ __align__(16) u16 sA[2][128 * 32];
  __shared__ __align__(16) u16 sB1[2][128 * 32];
  __shared__ __align__(16) u16 sB2[2][128 * 32];
  const int tid = threadIdx.x, w = tid >> 6, l = tid & 63;
  const int wm = w >> 1, wn = w & 1;
  const int m0 = blockIdx.y * 128, n0 = blockIdx.x * 128;
  const int K = p.K;
  const int NT = K >> 5;

  v4f acc1[4][4], acc2[4][4];
#pragma unroll
  for (int i = 0; i < 4; i++)
#pragma unroll
    for (int j = 0; j < 4; j++) {
      acc1[i][j] = (v4f){0.f, 0.f, 0.f, 0.f};
      acc2[i][j] = (v4f){0.f, 0.f, 0.f, 0.f};
    }

  int aOff[4], bOff[4];
#pragma unroll
  for (int i = 0; i < 4; i++) aOff[i] = swz(wm * 64 + i * 16 + (l & 15), l >> 4);
#pragma unroll
  for (int i = 0; i < 4; i++) bOff[i] = swz(wn * 64 + i * 16 + (l & 15), l >> 4);

  const int srow = tid >> 2, sg = tid & 3;
  const u16 *gA[2], *gB1[2], *gB2[2];
#pragma unroll
  for (int j = 0; j < 2; j++) {
    const int r = j * 64 + srow;
    const int co = (sg ^ ((r >> 1) & 3)) * 8;
    gA[j] = p.A + (size_t)(m0 + r) * K + co;
    gB1[j] = p.B1 + (size_t)(n0 + r) * K + co;
    gB2[j] = p.B2 + (size_t)(n0 + r) * K + co;
  }

  // prologue: stage tile 0 into buffer 0
#pragma unroll
  for (int j = 0; j < 2; j++) {
    gld16(&sA[0][j * 2048 + w * 512], gA[j]); gA[j] += 32;
    gld16(&sB1[0][j * 2048 + w * 512], gB1[j]); gB1[j] += 32;
    gld16(&sB2[0][j * 2048 + w * 512], gB2[j]); gB2[j] += 32;
  }
  wait_vm<0>();
  __builtin_amdgcn_s_barrier();

  auto body = [&](int T, auto cbT) {
    constexpr int CB = decltype(cbT)::value;
    constexpr int PB = CB ^ 1;
    // stage t+1 into the other buffer (readers use CB only)
    if (T + 1 < NT) {
#pragma unroll
      for (int j = 0; j < 2; j++) {
        gld16(&sA[PB][j * 2048 + w * 512], gA[j]); gA[j] += 32;
        gld16(&sB1[PB][j * 2048 + w * 512], gB1[j]); gB1[j] += 32;
        gld16(&sB2[PB][j * 2048 + w * 512], gB2[j]); gB2[j] += 32;
      }
    }
    v8s af[4], b1[4], b2[4];
#pragma unroll
    for (int i = 0; i < 4; i++) b1[i] = *(const v8s*)&sB1[CB][bOff[i]];
#pragma unroll
    for (int i = 0; i < 4; i++) af[i] = *(const v8s*)&sA[CB][aOff[i]];
#pragma unroll
    for (int i = 0; i < 4; i++) b2[i] = *(const v8s*)&sB2[CB][bOff[i]];
    wait_lgkm0();
    __builtin_amdgcn_s_setprio(1);
#pragma unroll
    for (int mt = 0; mt < 4; mt++)
#pragma unroll
      for (int nt = 0; nt < 4; nt++)
        acc1[mt][nt] = mfma16(af[mt], b1[nt], acc1[mt][nt]);
#pragma unroll
    for (int mt = 0; mt < 4; mt++)
#pragma unroll
      for (int nt = 0; nt < 4; nt++)
        acc2[mt][nt] = mfma16(af[mt], b2[nt], acc2[mt][nt]);
    __builtin_amdgcn_s_setprio(0);
    wait_vm<0>();
    __builtin_amdgcn_s_barrier();
  };

  int t = 0;
  for (; t + 2 <= NT; t += 2) {
    body(t, IC<0>{});
    body(t + 1, IC<1>{});
  }
  if (t < NT) body(t, IC<0>{});

#pragma unroll
  for (int mt = 0; mt < 4; mt++) {
#pragma unroll
    for (int nt = 0; nt < 4; nt++) {
      const int col = n0 + wn * 64 + nt * 16 + (l & 15);
      const float bb1 = p.bias1[col], bb2 = p.bias2[col];
#pragma unroll
      for (int r = 0; r < 4; r++) {
        const int row = m0 + wm * 64 + mt * 16 + (l >> 4) * 4 + r;
        const float v1 = acc1[mt][nt][r] + bb1;
        const float v2 = acc2[mt][nt][r] + bb2;
        p.out[(size_t)row * 4096 + col] = f2b(v1 * (1.f / (1.f + __expf(-v2))));
      }
    }
  }
}

// ---------- GEMM (4 waves, BM x 128) for OPROJ / FF2 ----------
template <int BM, int EPI, bool XS>
__global__ __launch_bounds__(256, 2) void gemm4(GemmArgs p) {
  constexpr int MT = BM / 32;
  constexpr int JA = BM / 64;
  constexpr int LD = JA + 2;
  __shared__ __align__(16) u16 sA[3][BM * 32];
  __shared__ __align__(16) u16 sB[3][128 * 32];
  const int tid = threadIdx.x, w = tid >> 6, l = tid & 63;
  const int wm = w >> 1, wn = w & 1;
  int bx = blockIdx.x, by = blockIdx.y;
  if (XS) xcd_map(gridDim.x, gridDim.y, bx, by);
  const int m0 = by * BM, n0 = bx * 128;
  const int K = p.K;
  const int NT = K >> 5;

  v4f acc[MT][4];
#pragma unroll
  for (int i = 0; i < MT; i++)
#pragma unroll
    for (int j = 0; j < 4; j++) acc[i][j] = (v4f){0.f, 0.f, 0.f, 0.f};

  int aOff[MT], bOff[4];
#pragma unroll
  for (int i = 0; i < MT; i++) aOff[i] = swz(wm * (MT * 16) + i * 16 + (l & 15), l >> 4);
#pragma unroll
  for (int i = 0; i < 4; i++) bOff[i] = swz(wn * 64 + i * 16 + (l & 15), l >> 4);

  const int srow = tid >> 2, sg = tid & 3;
  const u16* gA[JA];
  const u16* gB[2];
#pragma unroll
  for (int j = 0; j < JA; j++) {
    const int r = j * 64 + srow;
    gA[j] = p.A + (size_t)(m0 + r) * K + ((sg ^ ((r >> 1) & 3)) * 8);
  }
#pragma unroll
  for (int j = 0; j < 2; j++) {
    const int r = j * 64 + srow;
    gB[j] = p.Bt + (size_t)(n0 + r) * K + ((sg ^ ((r >> 1) & 3)) * 8);
  }

#pragma unroll
  for (int cb = 0; cb < 2; cb++) {
#pragma unroll
    for (int j = 0; j < JA; j++) { gld16(&sA[cb][j * 2048 + w * 512], gA[j]); gA[j] += 32; }
#pragma unroll
    for (int j = 0; j < 2; j++) { gld16(&sB[cb][j * 2048 + w * 512], gB[j]); gB[j] += 32; }
  }
  wait_vm<LD>();
  __builtin_amdgcn_s_barrier();

  auto body = [&](int T, auto cbT) {
    constexpr int CB = decltype(cbT)::value;
    constexpr int PB = (CB + 2) % 3;
    if (T + 2 < NT) {
#pragma unroll
      for (int j = 0; j < JA; j++) { gld16(&sA[PB][j * 2048 + w * 512], gA[j]); gA[j] += 32; }
#pragma unroll
      for (int j = 0; j < 2; j++) { gld16(&sB[PB][j * 2048 + w * 512], gB[j]); gB[j] += 32; }
    }
    v8s bf[4], af[MT];
#pragma unroll
    for (int i = 0; i < 4; i++) bf[i] = *(const v8s*)&sB[CB][bOff[i]];
#pragma unroll
    for (int i = 0; i < MT; i++) af[i] = *(const v8s*)&sA[CB][aOff[i]];
    wait_lgkm0();
    __builtin_amdgcn_s_setprio(1);
#pragma unroll
    for (int mt = 0; mt < MT; mt++)
#pragma unroll
      for (int nt = 0; nt < 4; nt++)
        acc[mt][nt] = mfma16(af[mt], bf[nt], acc[mt][nt]);
    __builtin_amdgcn_s_setprio(0);
    if (T < NT - 2) wait_vm<LD>();
    else wait_vm<0>();
    __builtin_amdgcn_s_barrier();
  };

  int t = 0;
  for (; t + 3 <= NT; t += 3) {
    body(t, IC<0>{});
    body(t + 1, IC<1>{});
    body(t + 2, IC<2>{});
  }
  if (t < NT) { body(t, IC<0>{}); t++; }
  if (t < NT) { body(t, IC<1>{}); }

#pragma unroll
  for (int mt = 0; mt < MT; mt++) {
#pragma unroll
    for (int nt = 0; nt < 4; nt++) {
      const int col = n0 + wn * 64 + nt * 16 + (l & 15);
#pragma unroll
      for (int r = 0; r < 4; r++) {
        const int row = m0 + wm * (MT * 16) + mt * 16 + (l >> 4) * 4 + r;
        float v = acc[mt][nt][r];
        if (EPI == GE_QKVG) {
          const int chunk = col >> 10, nl = col & 1023;
          const float* bias = (chunk == 0) ? p.bias0 : (chunk == 1) ? p.bias1
                              : (chunk == 2) ? p.bias2 : p.bias3;
          u16* dst = (chunk == 0) ? p.ob0 : (chunk == 1) ? p.ob1
                     : (chunk == 2) ? p.ob2 : p.ob3;
          v += bias[nl];
          if (chunk == 3) v = 1.f / (1.f + __expf(-v));
          dst[(size_t)row * 1024 + nl] = f2b(v);
        } else if (EPI == GE_OPROJ) {
          v += p.bias0[col];
          const size_t idx = (size_t)row * 1024 + col;
          p.outF[idx] = p.resF[idx] + b2f(p.gate[idx]) * v;
        } else {
          v += p.bias0[col];
          const size_t idx = (size_t)row * 1024 + col;
          const float u = p.resF[idx];
          const float h = (u - p.mean[row]) * p.rstd[row] * p.lnS[col] + p.lnB[col];
          p.outF[idx] = h + v;
        }
      }
    }
  }
}

// ---------- fused attention per (local b, h) ----------
__global__ __launch_bounds__(256, 2) void attn_kernel(
    const u16* __restrict__ QB, const u16* __restrict__ KB,
    const u16* __restrict__ VB, const float* __restrict__ rel,
    u16* __restrict__ AOB, int b_off) {
  __shared__ __align__(16) u16 sK[128 * 128];
  __shared__ __align__(16) u16 sP[128 * 128];
  const int tid = threadIdx.x, w = tid >> 6, l = tid & 63;
  const int bl = blockIdx.x >> 3, h = blockIdx.x & 7;
  const int bg = b_off + bl;
  const size_t base = ((size_t)bl * 128) * 1024 + h * 128;

#pragma unroll
  for (int i = 0; i < 8; i++) {
    const int c = i * 4 + w;
    gld16(&sK[c * 512], KB + base + (size_t)(c * 4 + (l >> 4)) * 1024 + (l & 15) * 8);
  }
  v8s qf[2][4];
#pragma unroll
  for (int mt = 0; mt < 2; mt++)
#pragma unroll
    for (int kb = 0; kb < 4; kb++)
      qf[mt][kb] = *(const v8s*)(QB + base + (size_t)(w * 32 + mt * 16 + (l & 15)) * 1024 +
                                 kb * 32 + (l >> 4) * 8);
  __syncthreads();

  v4f s[2][8];
#pragma unroll
  for (int mt = 0; mt < 2; mt++)
#pragma unroll
    for (int nt = 0; nt < 8; nt++) s[mt][nt] = (v4f){0.f, 0.f, 0.f, 0.f};
#pragma unroll
  for (int kb = 0; kb < 4; kb++) {
    v8s kf[8];
#pragma unroll
    for (int nt = 0; nt < 8; nt++)
      kf[nt] = *(const v8s*)&sK[(nt * 16 + (l & 15)) * 128 + kb * 32 + (l >> 4) * 8];
#pragma unroll
    for (int mt = 0; mt < 2; mt++)
#pragma unroll
      for (int nt = 0; nt < 8; nt++) s[mt][nt] = mfma16(qf[mt][kb], kf[nt], s[mt][nt]);
  }

  const float isc = 0.0883883476483184f;  // 1/sqrt(128)
#pragma unroll
  for (int mt = 0; mt < 2; mt++) {
#pragma unroll
    for (int r = 0; r < 4; r++) {
      const int q = w * 32 + mt * 16 + (l >> 4) * 4 + r;
      const float* br = rel + (size_t)(bg - q + 127) * 128 + (l & 15);
      float vv[8];
      float mx = -1e30f;
#pragma unroll
      for (int nt = 0; nt < 8; nt++) {
        const float t = s[mt][nt][r] * isc + br[nt * 16];
        vv[nt] = t;
        mx = fmaxf(mx, t);
      }
#pragma unroll
      for (int d = 1; d < 16; d <<= 1) mx = fmaxf(mx, __shfl_xor(mx, d));
      float sum = 0.f;
#pragma unroll
      for (int nt = 0; nt < 8; nt++) {
        const float e = __expf(vv[nt] - mx);
        vv[nt] = e;
        sum += e;
      }
#pragma unroll
      for (int d = 1; d < 16; d <<= 1) sum += __shfl_xor(sum, d);
      const float rs = 1.f / sum;
#pragma unroll
      for (int nt = 0; nt < 8; nt++)
        sP[q * 128 + nt * 16 + (l & 15)] = f2b(vv[nt] * rs);
    }
  }
  __syncthreads();

#pragma unroll
  for (int it = 0; it < 8; it++) {
    const int idx = it * 256 + tid;
    const int r = idx >> 4, c0 = (idx & 15) * 8;
    const uint4 u = *(const uint4*)(VB + base + (size_t)r * 1024 + c0);
    u16 tmp[8];
    *(uint4*)tmp = u;
#pragma unroll
    for (int j = 0; j < 8; j++) sK[(c0 + j) * 128 + r] = tmp[j];
  }
  __syncthreads();

  v4f o[2][8];
#pragma unroll
  for (int mt = 0; mt < 2; mt++)
#pragma unroll
    for (int nt = 0; nt < 8; nt++) o[mt][nt] = (v4f){0.f, 0.f, 0.f, 0.f};
#pragma unroll
  for (int kb = 0; kb < 4; kb++) {
    v8s pf[2], vf[8];
#pragma unroll
    for (int mt = 0; mt < 2; mt++)
      pf[mt] = *(const v8s*)&sP[(w * 32 + mt * 16 + (l & 15)) * 128 + kb * 32 + (l >> 4) * 8];
#pragma unroll
    for (int nt = 0; nt < 8; nt++)
      vf[nt] = *(const v8s*)&sK[(nt * 16 + (l & 15)) * 128 + kb * 32 + (l >> 4) * 8];
#pragma unroll
    for (int mt = 0; mt < 2; mt++)
#pragma unroll
      for (int nt = 0; nt < 8; nt++) o[mt][nt] = mfma16(pf[mt], vf[nt], o[mt][nt]);
  }
#pragma unroll
  for (int mt = 0; mt < 2; mt++)
#pragma unroll
    for (int nt = 0; nt < 8; nt++) {
      const int col = nt * 16 + (l & 15);
#pragma unroll
      for (int r = 0; r < 4; r++) {
        const int row = w * 32 + mt * 16 + (l >> 4) * 4 + r;
        AOB[base + (size_t)row * 1024 + col] = f2b(o[mt][nt][r]);
      }
    }
}

// ---------- LayerNorm over D=1024 ----------
template <int MODE>
__global__ __launch_bounds__(256) void ln_kernel(
    const float* __restrict__ U, const float* __restrict__ g,
    const float* __restrict__ be, u16* __restrict__ outB,
    float* __restrict__ meanP, float* __restrict__ rstdP,
    float* __restrict__ X, u16* __restrict__ XB, float survive) {
  const int row = blockIdx.x, tid = threadIdx.x, w = tid >> 6, l = tid & 63;
  const size_t off = (size_t)row * 1024 + tid * 4;
  const float4 v = *(const float4*)(U + off);
  float s = v.x + v.y + v.z + v.w;
  float s2 = v.x * v.x + v.y * v.y + v.z * v.z + v.w * v.w;
#pragma unroll
  for (int d = 1; d < 64; d <<= 1) {
    s += __shfl_xor(s, d);
    s2 += __shfl_xor(s2, d);
  }
  __shared__ float red[8];
  if (l == 0) {
    red[w] = s;
    red[4 + w] = s2;
  }
  __syncthreads();
  s = red[0] + red[1] + red[2] + red[3];
  s2 = red[4] + red[5] + red[6] + red[7];
  const float mean = s * (1.f / 1024.f);
  const float var = s2 * (1.f / 1024.f) - mean * mean;
  const float rstd = rsqrtf(var + 1e-6f);
  const float4 gg = *(const float4*)(g + tid * 4);
  const float4 bb = *(const float4*)(be + tid * 4);
  float o0 = (v.x - mean) * rstd * gg.x + bb.x;
  float o1 = (v.y - mean) * rstd * gg.y + bb.y;
  float o2 = (v.z - mean) * rstd * gg.z + bb.z;
  float o3 = (v.w - mean) * rstd * gg.w + bb.w;
  if (MODE == 1) {
    ushort4 pb = {f2b(o0), f2b(o1), f2b(o2), f2b(o3)};
    *(ushort4*)(outB + off) = pb;
    if (tid == 0) {
      meanP[row] = mean;
      rstdP[row] = rstd;
    }
  } else {
    const float4 xv = *(const float4*)(X + off);
    const float n0 = xv.x + survive * (o0 - xv.x);
    const float n1 = xv.y + survive * (o1 - xv.y);
    const float n2 = xv.z + survive * (o2 - xv.z);
    const float n3 = xv.w + survive * (o3 - xv.w);
    *(float4*)(X + off) = make_float4(n0, n1, n2, n3);
    ushort4 pb = {f2b(n0), f2b(n1), f2b(n2), f2b(n3)};
    *(ushort4*)(XB + off) = pb;
  }
}

// ---------- pooling: 4 blocks per batch, 256 cols each ----------
__global__ __launch_bounds__(256) void pool_kernel(const float* __restrict__ X,
                                                   const float* __restrict__ other,
                                                   float* __restrict__ pooled) {
  const int b = blockIdx.x >> 2, c = blockIdx.x & 3, tid = threadIdx.x;
  const int d = c * 256 + tid;
  float sm = 0.f, mx = -1e30f;
  for (int ll = 0; ll < 128; ll++) {
    const float v = X[((size_t)b * 128 + ll) * 1024 + d];
    sm += v;
    mx = fmaxf(mx, v);
  }
  pooled[b * 2112 + d] = sm * (1.f / 128.f);
  pooled[b * 2112 + 1024 + d] = mx;
  if (c == 0 && tid < 64) pooled[b * 2112 + 2048 + tid] = other[b * 64 + tid];
}

// ---------- head ----------
__global__ __launch_bounds__(128) void head_kernel(
    const float* __restrict__ pooled, const float* __restrict__ Wd1,
    const float* __restrict__ bd1, const float* __restrict__ g3,
    const float* __restrict__ b3, const float* __restrict__ Wd2,
    const float* __restrict__ bd2, const float* __restrict__ Wout,
    const float* __restrict__ bout, float* __restrict__ out) {
  const int b = blockIdx.x, n = threadIdx.x, w = n >> 6, l = n & 63;
  __shared__ float sp[2112];
  __shared__ float sy[128];
  __shared__ float r2[4];
  __shared__ float rr[2];
  for (int i = n; i < 2112; i += 128) sp[i] = pooled[b * 2112 + i];
  __syncthreads();
  float a = bd1[n];
  for (int k = 0; k < 2112; k++) a = fmaf(sp[k], Wd1[k * 128 + n], a);
  a = fmaxf(a, 0.f);
  float s = a, s2 = a * a;
#pragma unroll
  for (int d = 1; d < 64; d <<= 1) {
    s += __shfl_xor(s, d);
    s2 += __shfl_xor(s2, d);
  }
  if (l == 0) {
    r2[w] = s;
    r2[2 + w] = s2;
  }
  __syncthreads();
  s = r2[0] + r2[1];
  s2 = r2[2] + r2[3];
  const float mean = s * (1.f / 128.f);
  const float var = s2 * (1.f / 128.f) - mean * mean;
  const float yn = (a - mean) * rsqrtf(var + 1e-6f) * g3[n] + b3[n];
  sy[n] = yn;
  __syncthreads();
  float a2 = bd2[n];
  for (int k = 0; k < 128; k++) a2 = fmaf(sy[k], Wd2[k * 128 + n], a2);
  a2 = fmaxf(a2, 0.f);
  float t = a2 * Wout[n];
#pragma unroll
  for (int d = 1; d < 64; d <<= 1) t += __shfl_xor(t, d);
  if (l == 0) rr[w] = t;
  __syncthreads();
  if (n == 0) out[b] = rr[0] + rr[1] + bout[0];
}

// ---------- launcher ----------
extern "C" void kernel_launch(void* const* d_in, const int* in_sizes, int n_in,
                              void* d_out, int out_size, void* d_ws,
                              size_t ws_size, hipStream_t stream) {
  (void)in_sizes; (void)n_in; (void)out_size;
  const float* cgm = (const float*)d_in[0];
  const float* other = (const float*)d_in[1];
  const float* W_in = (const float*)d_in[2];
  const float* b_in = (const float*)d_in[3];
  const float* rel = (const float*)d_in[4];
  const float* Wq = (const float*)d_in[5];
  const float* bq = (const float*)d_in[6];
  const float* Wk = (const float*)d_in[7];
  const float* bk = (const float*)d_in[8];
  const float* Wv = (const float*)d_in[9];
  const float* bv = (const float*)d_in[10];
  const float* Wo = (const float*)d_in[11];
  const float* bo = (const float*)d_in[12];
  const float* Wg = (const float*)d_in[13];
  const float* bg = (const float*)d_in[14];
  const float* ln1s = (const float*)d_in[15];
  const float* ln1b = (const float*)d_in[16];
  const float* Wf1 = (const float*)d_in[17];
  const float* bf1 = (const float*)d_in[18];
  const float* Wfg = (const float*)d_in[19];
  const float* bfg = (const float*)d_in[20];
  const float* Wf2 = (const float*)d_in[21];
  const float* bf2 = (const float*)d_in[22];
  const float* ln2s = (const float*)d_in[23];
  const float* ln2b = (const float*)d_in[24];
  const float* Wd1 = (const float*)d_in[25];
  const float* bd1 = (const float*)d_in[26];
  const float* l3s = (const float*)d_in[27];
  const float* l3b = (const float*)d_in[28];
  const float* Wd2 = (const float*)d_in[29];
  const float* bd2 = (const float*)d_in[30];
  const float* Wout = (const float*)d_in[31];
  const float* bout = (const float*)d_in[32];
  float* out = (float*)d_out;

  // ---- adaptive memory plan (R multiple of 256) ----
  const size_t WT_LAYER = 17825792ull;
  const size_t POOLED_B = 1081344ull;
  const size_t PER_ROW = 20488ull;
  int R = 0;
  bool all_mode = true;
  for (int cand = 16384; cand >= 256; cand >>= 1)
    if (2 * WT_LAYER * 2 + POOLED_B + (size_t)cand * PER_ROW <= ws_size) { R = cand; break; }
  if (!R) {
    all_mode = false;
    for (int cand = 16384; cand >= 256; cand >>= 1)
      if (WT_LAYER * 2 + POOLED_B + (size_t)cand * PER_ROW <= ws_size) { R = cand; break; }
  }
  if (!R) return;

  char* p = (char*)d_ws;
  u16* wt = (u16*)p;
  p += (all_mode ? 2 : 1) * WT_LAYER * 2;
  float* pooled = (float*)p; p += POOLED_B;
  float* meanP = (float*)p; p += (size_t)R * 4;
  float* rstdP = (float*)p; p += (size_t)R * 4;
  float* X = (float*)p; p += (size_t)R * 4096;
  u16* XB = (u16*)p; p += (size_t)R * 2048;
  u16* QKVG = (u16*)p; p += (size_t)R * 8192;
  u16* ABH = (u16*)p; p += (size_t)R * 2048;
  float* U = (float*)p; p += (size_t)R * 4096;

  u16* QB = QKVG;
  u16* KB = QKVG + (size_t)R * 1024;
  u16* VB = QKVG + (size_t)R * 2048;
  u16* GB = QKVG + (size_t)R * 3072;
  u16* FB = QKVG;  // [R][4096] alias, lifetime-disjoint
  u16* AOB = ABH;
  u16* HB = ABH;

  const size_t OFF_QKVG = 0, OFF_O = 4194304, OFF_F1 = 5242880,
               OFF_FG = 9437184, OFF_F2 = 13631488;

  auto convert_layer = [&](int i, u16* dst) {
    {
      TransArgs t{};
      t.src[0] = Wq + (size_t)i * 1048576; t.dst[0] = dst + OFF_QKVG;
      t.src[1] = Wk + (size_t)i * 1048576; t.dst[1] = dst + OFF_QKVG + 1048576;
      t.src[2] = Wv + (size_t)i * 1048576; t.dst[2] = dst + OFF_QKVG + 2097152;
      t.src[3] = Wg + (size_t)i * 1048576; t.dst[3] = dst + OFF_QKVG + 3145728;
      t.src[4] = Wo + (size_t)i * 1048576; t.dst[4] = dst + OFF_O;
      t.K = 1024; t.N = 1024;
      wtrans<<<dim3(32, 32, 5), 256, 0, stream>>>(t);
    }
    {
      TransArgs t{};
      t.src[0] = Wf1 + (size_t)i * 4194304; t.dst[0] = dst + OFF_F1;
      t.src[1] = Wfg + (size_t)i * 4194304; t.dst[1] = dst + OFF_FG;
      t.K = 1024; t.N = 4096;
      wtrans<<<dim3(128, 32, 2), 256, 0, stream>>>(t);
    }
    {
      TransArgs t{};
      t.src[0] = Wf2 + (size_t)i * 4194304; t.dst[0] = dst + OFF_F2;
      t.K = 4096; t.N = 1024;
      wtrans<<<dim3(32, 128, 1), 256, 0, stream>>>(t);
    }
  };

  if (all_mode) {
    convert_layer(0, wt);
    convert_layer(1, wt + WT_LAYER);
  }

  const int Bc = R / 128;
  const int nchunks = 16384 / R;

  for (int c = 0; c < nchunks; c++) {
    const int r0 = c * R;
    const int b0 = r0 / 128;

    inproj<<<dim3(8, R / 32), 256, 0, stream>>>(cgm + (size_t)r0 * 32, W_in, b_in, X, XB);

    for (int i = 0; i < 2; i++) {
      u16* W;
      if (all_mode) {
        W = wt + (size_t)i * WT_LAYER;
      } else {
        convert_layer(i, wt);
        W = wt;
      }

      {
        GemmArgs g{};
        g.A = XB; g.Bt = W + OFF_QKVG;
        g.K = 1024; g.N = 4096;
        g.bias0 = bq + i * 1024; g.bias1 = bk + i * 1024;
        g.bias2 = bv + i * 1024; g.bias3 = bg + i * 1024;
        g.ob0 = QB; g.ob1 = KB; g.ob2 = VB; g.ob3 = GB;
        gemm8w<GE_QKVG><<<dim3(16, R / 256), 512, 0, stream>>>(g);
      }
      attn_kernel<<<dim3(Bc * 8), 256, 0, stream>>>(
          QB, KB, VB, rel + (size_t)i * 255 * 128, AOB, b0);
      {
        GemmArgs g{};
        g.A = AOB; g.Bt = W + OFF_O;
        g.K = 1024; g.N = 1024;
        g.bias0 = bo + i * 1024;
        g.resF = X; g.gate = GB; g.outF = U;
        gemm4<128, GE_OPROJ, true><<<dim3(8, R / 128), 256, 0, stream>>>(g);
      }
      ln_kernel<1><<<R, 256, 0, stream>>>(U, ln1s + i * 1024, ln1b + i * 1024,
                                          HB, meanP, rstdP, nullptr, nullptr, 0.f);
      {
        DualArgs dd{};
        dd.A = HB; dd.B1 = W + OFF_F1; dd.B2 = W + OFF_FG;
        dd.bias1 = bf1 + i * 4096; dd.bias2 = bfg + i * 4096;
        dd.out = FB; dd.K = 1024;
        dual2b<<<dim3(32, R / 128), 256, 0, stream>>>(dd);
      }
      {
        GemmArgs g{};
        g.A = FB; g.Bt = W + OFF_F2;
        g.K = 4096; g.N = 1024;
        g.bias0 = bf2 + i * 1024;
        g.resF = U; g.outF = U;
        g.mean = meanP; g.rstd = rstdP;
        g.lnS = ln1s + i * 1024; g.lnB = ln1b + i * 1024;
        gemm4<128, GE_FF2, true><<<dim3(8, R / 128), 256, 0, stream>>>(g);
      }
      const float survive = (i == 0) ? 1.0f : 0.5f;
      ln_kernel<2><<<R, 256, 0, stream>>>(U, ln2s + i * 1024, ln2b + i * 1024,
                                          nullptr, nullptr, nullptr, X, XB, survive);
    }
    pool_kernel<<<Bc * 4, 256, 0, stream>>>(X, other + (size_t)b0 * 64,
                                            pooled + (size_t)b0 * 2112);
  }
  head_kernel<<<128, 128, 0, stream>>>(pooled, Wd1, bd1, l3s, l3b, Wd2, bd2,
                                       Wout, bout, out);
}

// Round 13
// 1794.077 us; speedup vs baseline: 2.0161x; 2.0161x over previous
//
#include <hip/hip_runtime.h>
#include <stdint.h>

// ---------- common types / helpers ----------
typedef unsigned short u16;
typedef __bf16 v8bf __attribute__((ext_vector_type(8)));
typedef short v8s  __attribute__((ext_vector_type(8)));
typedef float v4f  __attribute__((ext_vector_type(4)));

template <int N> struct IC { static constexpr int value = N; };

__device__ __forceinline__ u16 f2b(float f) {
  unsigned int x = __float_as_uint(f);
  x += 0x7fffu + ((x >> 16) & 1u);   // RNE
  return (u16)(x >> 16);
}
__device__ __forceinline__ float b2f(u16 u) {
  return __uint_as_float(((unsigned int)u) << 16);
}

// async global->LDS, 16B per lane; lds arg = wave-uniform base, HW adds lane*16
__device__ __forceinline__ void gld16(void* lds, const void* g) {
  __builtin_amdgcn_global_load_lds(
      (const __attribute__((address_space(1))) void*)g,
      (__attribute__((address_space(3))) void*)lds, 16, 0, 0);
}

__device__ __forceinline__ v4f mfma16(v8s a, v8s b, v4f c) {
  return __builtin_amdgcn_mfma_f32_16x16x32_bf16(
      __builtin_bit_cast(v8bf, a), __builtin_bit_cast(v8bf, b), c, 0, 0, 0);
}

template <int N>
__device__ __forceinline__ void wait_vm() {
  if constexpr (N == 0) asm volatile("s_waitcnt vmcnt(0)" ::: "memory");
  else if constexpr (N == 4) asm volatile("s_waitcnt vmcnt(4)" ::: "memory");
  else if constexpr (N == 6) asm volatile("s_waitcnt vmcnt(6)" ::: "memory");
  else asm volatile("s_waitcnt vmcnt(8)" ::: "memory");
}
__device__ __forceinline__ void wait_lgkm0() {
  asm volatile("s_waitcnt lgkmcnt(0)" ::: "memory");
}

// conflict-free swizzle for [ROWS][32] bf16 K-tiles (64B rows):
// 16B-granule g (0..3) of row r stored at granule g ^ ((r>>1)&3).
// (verified: SQ_LDS_BANK_CONFLICT == 0)
__device__ __forceinline__ int swz(int r, int g) {
  return r * 32 + ((g ^ ((r >> 1) & 3)) * 8);
}

// XCD-aware chunked block swizzle (helps K=4096 small-N GEMMs; hurts dual/QKVG geometry)
__device__ __forceinline__ void xcd_map(int gx, int gy, int& bx, int& by) {
  const int nwg = gx * gy;
  int lin = blockIdx.y * gx + blockIdx.x;
  const int per = nwg >> 3;
  lin = (lin & 7) * per + (lin >> 3);
  bx = lin % gx;
  by = lin / gx;
}

// ---------- weight transpose+convert: src [K,N] f32 -> dst [N,K] bf16 ----------
struct TransArgs {
  const float* src[10];
  u16* dst[10];
  int K, N;
};
__global__ __launch_bounds__(256) void wtrans(TransArgs p) {
  const float* src = p.src[blockIdx.z];
  u16* dst = p.dst[blockIdx.z];
  __shared__ float t[32][33];
  const int tx = threadIdx.x & 31, ty = threadIdx.x >> 5;
  const int n0 = blockIdx.x * 32, k0 = blockIdx.y * 32;
#pragma unroll
  for (int j = 0; j < 4; j++)
    t[ty * 4 + j][tx] = src[(size_t)(k0 + ty * 4 + j) * p.N + n0 + tx];
  __syncthreads();
#pragma unroll
  for (int j = 0; j < 4; j++)
    dst[(size_t)(n0 + ty * 4 + j) * p.K + k0 + tx] = f2b(t[tx][ty * 4 + j]);
}

// ---------- input projection: block = 32 rows x 128 cols, W amortized 16x ----
__global__ __launch_bounds__(256) void inproj(const float* __restrict__ cgm,
                                              const float* __restrict__ Win,
                                              const float* __restrict__ bin,
                                              float* __restrict__ X,
                                              u16* __restrict__ XB) {
  __shared__ float sc[32][33];
  const int tid = threadIdx.x;
  const int m0 = blockIdx.y * 32, n0 = blockIdx.x * 128;
  for (int i = tid; i < 1024; i += 256)
    sc[i >> 5][i & 31] = cgm[(size_t)(m0 + (i >> 5)) * 32 + (i & 31)];
  __syncthreads();
  const int n = n0 + (tid & 127);
  const int rh = (tid >> 7) * 16;
  float acc[16];
  const float b = bin[n];
#pragma unroll
  for (int r = 0; r < 16; r++) acc[r] = b;
  for (int k = 0; k < 32; k++) {
    const float wv = Win[k * 1024 + n];
#pragma unroll
    for (int r = 0; r < 16; r++) acc[r] = fmaf(sc[rh + r][k], wv, acc[r]);
  }
#pragma unroll
  for (int r = 0; r < 16; r++) {
    const size_t idx = (size_t)(m0 + rh + r) * 1024 + n;
    X[idx] = acc[r];
    XB[idx] = f2b(acc[r]);
  }
}

#define GE_QKVG 0
#define GE_OPROJ 1
#define GE_FF2 2

struct GemmArgs {
  const u16* A;
  const u16* Bt;
  const float *bias0, *bias1, *bias2, *bias3;
  u16 *ob0, *ob1, *ob2, *ob3;
  const float* resF;
  const u16* gate;
  float* outF;
  const float *mean, *rstd, *lnS, *lnB;
  int K, N;
};

// ---------- 8-wave phase-pipelined GEMM: BM=256, BN=256, BK=32, 4 LDS bufs ----
template <int EPI>
__global__ __launch_bounds__(512, 2) void gemm8w(GemmArgs p) {
  __shared__ __align__(16) u16 sA[4][256 * 32];
  __shared__ __align__(16) u16 sB[4][256 * 32];
  const int tid = threadIdx.x, w = tid >> 6, l = tid & 63;
  const int wm = w >> 2, wn = w & 3;   // 2M x 4N waves, per-wave 128x64
  const int m0 = blockIdx.y * 256, n0 = blockIdx.x * 256;
  const int K = p.K, NT = K >> 5;

  v4f acc[8][4];
#pragma unroll
  for (int i = 0; i < 8; i++)
#pragma unroll
    for (int j = 0; j < 4; j++) acc[i][j] = (v4f){0.f, 0.f, 0.f, 0.f};

  int aOff[8], bOff[4];
#pragma unroll
  for (int i = 0; i < 8; i++) aOff[i] = swz(wm * 128 + i * 16 + (l & 15), l >> 4);
#pragma unroll
  for (int i = 0; i < 4; i++) bOff[i] = swz(wn * 64 + i * 16 + (l & 15), l >> 4);

  const int srow = tid >> 2, sg = tid & 3;
  const u16 *gA[2], *gB[2];
#pragma unroll
  for (int j = 0; j < 2; j++) {
    const int r = j * 128 + srow;
    const int co = (sg ^ ((r >> 1) & 3)) * 8;
    gA[j] = p.A + (size_t)(m0 + r) * K + co;
    gB[j] = p.Bt + (size_t)(n0 + r) * K + co;
  }

  // prologue: stage tiles 0,1
#pragma unroll
  for (int b = 0; b < 2; b++) {
#pragma unroll
    for (int j = 0; j < 2; j++) { gld16(&sA[b][j * 4096 + w * 512], gA[j]); gA[j] += 32; }
#pragma unroll
    for (int j = 0; j < 2; j++) { gld16(&sB[b][j * 4096 + w * 512], gB[j]); gB[j] += 32; }
  }
  wait_vm<4>();
  __builtin_amdgcn_s_barrier();

  auto tb = [&](int T, auto rbT) {
    constexpr int RB = decltype(rbT)::value;
    constexpr int SB = (RB + 2) & 3;
    const bool st = (T + 2) < NT;
    // ---- phase 0: B frags + A frags 0-3; stage next A ----
    v8s bf[4], af[4];
#pragma unroll
    for (int i = 0; i < 4; i++) bf[i] = *(const v8s*)&sB[RB][bOff[i]];
#pragma unroll
    for (int i = 0; i < 4; i++) af[i] = *(const v8s*)&sA[RB][aOff[i]];
    if (st) {
#pragma unroll
      for (int j = 0; j < 2; j++) { gld16(&sA[SB][j * 4096 + w * 512], gA[j]); gA[j] += 32; }
    }
    __builtin_amdgcn_s_barrier();
    wait_lgkm0();
    __builtin_amdgcn_s_setprio(1);
#pragma unroll
    for (int mt = 0; mt < 4; mt++)
#pragma unroll
      for (int nt = 0; nt < 4; nt++)
        acc[mt][nt] = mfma16(af[mt], bf[nt], acc[mt][nt]);
    __builtin_amdgcn_s_setprio(0);
    // ---- phase 1: A frags 4-7; stage next B; tile-boundary vmcnt ----
    v8s af1[4];
#pragma unroll
    for (int i = 0; i < 4; i++) af1[i] = *(const v8s*)&sA[RB][aOff[4 + i]];
    if (st) {
#pragma unroll
      for (int j = 0; j < 2; j++) { gld16(&sB[SB][j * 4096 + w * 512], gB[j]); gB[j] += 32; }
      wait_vm<4>();
    } else if (T + 2 == NT) {
      wait_vm<0>();
    }
    __builtin_amdgcn_s_barrier();
    wait_lgkm0();
    __builtin_amdgcn_s_setprio(1);
#pragma unroll
    for (int mt = 0; mt < 4; mt++)
#pragma unroll
      for (int nt = 0; nt < 4; nt++)
        acc[4 + mt][nt] = mfma16(af1[mt], bf[nt], acc[4 + mt][nt]);
    __builtin_amdgcn_s_setprio(0);
  };

  for (int t = 0; t < NT; t += 4) {
    tb(t, IC<0>{});
    tb(t + 1, IC<1>{});
    tb(t + 2, IC<2>{});
    tb(t + 3, IC<3>{});
  }

#pragma unroll
  for (int mt = 0; mt < 8; mt++) {
#pragma unroll
    for (int nt = 0; nt < 4; nt++) {
      const int col = n0 + wn * 64 + nt * 16 + (l & 15);
#pragma unroll
      for (int r = 0; r < 4; r++) {
        const int row = m0 + wm * 128 + mt * 16 + (l >> 4) * 4 + r;
        float v = acc[mt][nt][r];
        if (EPI == GE_QKVG) {
          const int chunk = col >> 10, nl = col & 1023;
          const float* bias = (chunk == 0) ? p.bias0 : (chunk == 1) ? p.bias1
                              : (chunk == 2) ? p.bias2 : p.bias3;
          u16* dst = (chunk == 0) ? p.ob0 : (chunk == 1) ? p.ob1
                     : (chunk == 2) ? p.ob2 : p.ob3;
          v += bias[nl];
          if (chunk == 3) v = 1.f / (1.f + __expf(-v));
          dst[(size_t)row * 1024 + nl] = f2b(v);
        } else if (EPI == GE_OPROJ) {
          v += p.bias0[col];
          const size_t idx = (size_t)row * 1024 + col;
          p.outF[idx] = p.resF[idx] + b2f(p.gate[idx]) * v;
        } else {
          v += p.bias0[col];
          const size_t idx = (size_t)row * 1024 + col;
          const float u = p.resF[idx];
          const float h = (u - p.mean[row]) * p.rstd[row] * p.lnS[col] + p.lnB[col];
          p.outF[idx] = h + v;
        }
      }
    }
  }
}

// ---------- 8-wave phase-pipelined dual GEMM: BM=256, BN=128, BK=32 ----------
struct DualArgs {
  const u16* A;
  const u16 *B1, *B2;
  const float *bias1, *bias2;
  u16* out;
  int K;
};
__global__ __launch_bounds__(512, 2) void dual8w(DualArgs p) {
  __shared__ __align__(16) u16 sA[4][256 * 32];
  __shared__ __align__(16) u16 sB1[4][128 * 32];
  __shared__ __align__(16) u16 sB2[4][128 * 32];
  const int tid = threadIdx.x, w = tid >> 6, l = tid & 63;
  const int wm = w >> 2, wn = w & 3;   // per-wave 128 x 32 (per B matrix)
  const int m0 = blockIdx.y * 256, n0 = blockIdx.x * 128;
  const int K = p.K, NT = K >> 5;

  v4f acc1[8][2], acc2[8][2];
#pragma unroll
  for (int i = 0; i < 8; i++)
#pragma unroll
    for (int j = 0; j < 2; j++) {
      acc1[i][j] = (v4f){0.f, 0.f, 0.f, 0.f};
      acc2[i][j] = (v4f){0.f, 0.f, 0.f, 0.f};
    }

  int aOff[8], bOff[2];
#pragma unroll
  for (int i = 0; i < 8; i++) aOff[i] = swz(wm * 128 + i * 16 + (l & 15), l >> 4);
#pragma unroll
  for (int i = 0; i < 2; i++) bOff[i] = swz(wn * 32 + i * 16 + (l & 15), l >> 4);

  const int srow = tid >> 2, sg = tid & 3;
  const u16 *gA[2], *gB1, *gB2;
#pragma unroll
  for (int j = 0; j < 2; j++) {
    const int r = j * 128 + srow;
    gA[j] = p.A + (size_t)(m0 + r) * K + ((sg ^ ((r >> 1) & 3)) * 8);
  }
  {
    const int co = (sg ^ ((srow >> 1) & 3)) * 8;
    gB1 = p.B1 + (size_t)(n0 + srow) * K + co;
    gB2 = p.B2 + (size_t)(n0 + srow) * K + co;
  }

  // prologue: tiles 0,1
#pragma unroll
  for (int b = 0; b < 2; b++) {
#pragma unroll
    for (int j = 0; j < 2; j++) { gld16(&sA[b][j * 4096 + w * 512], gA[j]); gA[j] += 32; }
    gld16(&sB1[b][w * 512], gB1); gB1 += 32;
    gld16(&sB2[b][w * 512], gB2); gB2 += 32;
  }
  wait_vm<4>();
  __builtin_amdgcn_s_barrier();

  auto tb = [&](int T, auto rbT) {
    constexpr int RB = decltype(rbT)::value;
    constexpr int SB = (RB + 2) & 3;
    const bool st = (T + 2) < NT;
    // ---- phase 0 ----
    v8s b1[2], b2[2], af[4];
#pragma unroll
    for (int i = 0; i < 2; i++) b1[i] = *(const v8s*)&sB1[RB][bOff[i]];
#pragma unroll
    for (int i = 0; i < 2; i++) b2[i] = *(const v8s*)&sB2[RB][bOff[i]];
#pragma unroll
    for (int i = 0; i < 4; i++) af[i] = *(const v8s*)&sA[RB][aOff[i]];
    if (st) {
#pragma unroll
      for (int j = 0; j < 2; j++) { gld16(&sA[SB][j * 4096 + w * 512], gA[j]); gA[j] += 32; }
    }
    __builtin_amdgcn_s_barrier();
    wait_lgkm0();
    __builtin_amdgcn_s_setprio(1);
#pragma unroll
    for (int mt = 0; mt < 4; mt++)
#pragma unroll
      for (int nt = 0; nt < 2; nt++) {
        acc1[mt][nt] = mfma16(af[mt], b1[nt], acc1[mt][nt]);
        acc2[mt][nt] = mfma16(af[mt], b2[nt], acc2[mt][nt]);
      }
    __builtin_amdgcn_s_setprio(0);
    // ---- phase 1 ----
    v8s af1[4];
#pragma unroll
    for (int i = 0; i < 4; i++) af1[i] = *(const v8s*)&sA[RB][aOff[4 + i]];
    if (st) {
      gld16(&sB1[SB][w * 512], gB1); gB1 += 32;
      gld16(&sB2[SB][w * 512], gB2); gB2 += 32;
      wait_vm<4>();
    } else if (T + 2 == NT) {
      wait_vm<0>();
    }
    __builtin_amdgcn_s_barrier();
    wait_lgkm0();
    __builtin_amdgcn_s_setprio(1);
#pragma unroll
    for (int mt = 0; mt < 4; mt++)
#pragma unroll
      for (int nt = 0; nt < 2; nt++) {
        acc1[4 + mt][nt] = mfma16(af1[mt], b1[nt], acc1[4 + mt][nt]);
        acc2[4 + mt][nt] = mfma16(af1[mt], b2[nt], acc2[4 + mt][nt]);
      }
    __builtin_amdgcn_s_setprio(0);
  };

  for (int t = 0; t < NT; t += 4) {
    tb(t, IC<0>{});
    tb(t + 1, IC<1>{});
    tb(t + 2, IC<2>{});
    tb(t + 3, IC<3>{});
  }

#pragma unroll
  for (int mt = 0; mt < 8; mt++) {
#pragma unroll
    for (int nt = 0; nt < 2; nt++) {
      const int col = n0 + wn * 32 + nt * 16 + (l & 15);
      const float bb1 = p.bias1[col], bb2 = p.bias2[col];
#pragma unroll
      for (int r = 0; r < 4; r++) {
        const int row = m0 + wm * 128 + mt * 16 + (l >> 4) * 4 + r;
        const float v1 = acc1[mt][nt][r] + bb1;
        const float v2 = acc2[mt][nt][r] + bb2;
        p.out[(size_t)row * 4096 + col] = f2b(v1 * (1.f / (1.f + __expf(-v2))));
      }
    }
  }
}

// ---------- GEMM (4 waves, BM x 128) for OPROJ / FF2 ----------
template <int BM, int EPI, bool XS>
__global__ __launch_bounds__(256, 2) void gemm4(GemmArgs p) {
  constexpr int MT = BM / 32;
  constexpr int JA = BM / 64;
  constexpr int LD = JA + 2;
  __shared__ __align__(16) u16 sA[3][BM * 32];
  __shared__ __align__(16) u16 sB[3][128 * 32];
  const int tid = threadIdx.x, w = tid >> 6, l = tid & 63;
  const int wm = w >> 1, wn = w & 1;
  int bx = blockIdx.x, by = blockIdx.y;
  if (XS) xcd_map(gridDim.x, gridDim.y, bx, by);
  const int m0 = by * BM, n0 = bx * 128;
  const int K = p.K;
  const int NT = K >> 5;

  v4f acc[MT][4];
#pragma unroll
  for (int i = 0; i < MT; i++)
#pragma unroll
    for (int j = 0; j < 4; j++) acc[i][j] = (v4f){0.f, 0.f, 0.f, 0.f};

  int aOff[MT], bOff[4];
#pragma unroll
  for (int i = 0; i < MT; i++) aOff[i] = swz(wm * (MT * 16) + i * 16 + (l & 15), l >> 4);
#pragma unroll
  for (int i = 0; i < 4; i++) bOff[i] = swz(wn * 64 + i * 16 + (l & 15), l >> 4);

  const int srow = tid >> 2, sg = tid & 3;
  const u16* gA[JA];
  const u16* gB[2];
#pragma unroll
  for (int j = 0; j < JA; j++) {
    const int r = j * 64 + srow;
    gA[j] = p.A + (size_t)(m0 + r) * K + ((sg ^ ((r >> 1) & 3)) * 8);
  }
#pragma unroll
  for (int j = 0; j < 2; j++) {
    const int r = j * 64 + srow;
    gB[j] = p.Bt + (size_t)(n0 + r) * K + ((sg ^ ((r >> 1) & 3)) * 8);
  }

#pragma unroll
  for (int cb = 0; cb < 2; cb++) {
#pragma unroll
    for (int j = 0; j < JA; j++) { gld16(&sA[cb][j * 2048 + w * 512], gA[j]); gA[j] += 32; }
#pragma unroll
    for (int j = 0; j < 2; j++) { gld16(&sB[cb][j * 2048 + w * 512], gB[j]); gB[j] += 32; }
  }
  wait_vm<LD>();
  __builtin_amdgcn_s_barrier();

  auto body = [&](int T, auto cbT) {
    constexpr int CB = decltype(cbT)::value;
    constexpr int PB = (CB + 2) % 3;
    if (T + 2 < NT) {
#pragma unroll
      for (int j = 0; j < JA; j++) { gld16(&sA[PB][j * 2048 + w * 512], gA[j]); gA[j] += 32; }
#pragma unroll
      for (int j = 0; j < 2; j++) { gld16(&sB[PB][j * 2048 + w * 512], gB[j]); gB[j] += 32; }
    }
    v8s bf[4], af[MT];
#pragma unroll
    for (int i = 0; i < 4; i++) bf[i] = *(const v8s*)&sB[CB][bOff[i]];
#pragma unroll
    for (int i = 0; i < MT; i++) af[i] = *(const v8s*)&sA[CB][aOff[i]];
    wait_lgkm0();
    __builtin_amdgcn_s_setprio(1);
#pragma unroll
    for (int mt = 0; mt < MT; mt++)
#pragma unroll
      for (int nt = 0; nt < 4; nt++)
        acc[mt][nt] = mfma16(af[mt], bf[nt], acc[mt][nt]);
    __builtin_amdgcn_s_setprio(0);
    if (T < NT - 2) wait_vm<LD>();
    else wait_vm<0>();
    __builtin_amdgcn_s_barrier();
  };

  int t = 0;
  for (; t + 3 <= NT; t += 3) {
    body(t, IC<0>{});
    body(t + 1, IC<1>{});
    body(t + 2, IC<2>{});
  }
  if (t < NT) { body(t, IC<0>{}); t++; }
  if (t < NT) { body(t, IC<1>{}); }

#pragma unroll
  for (int mt = 0; mt < MT; mt++) {
#pragma unroll
    for (int nt = 0; nt < 4; nt++) {
      const int col = n0 + wn * 64 + nt * 16 + (l & 15);
#pragma unroll
      for (int r = 0; r < 4; r++) {
        const int row = m0 + wm * (MT * 16) + mt * 16 + (l >> 4) * 4 + r;
        float v = acc[mt][nt][r];
        if (EPI == GE_QKVG) {
          const int chunk = col >> 10, nl = col & 1023;
          const float* bias = (chunk == 0) ? p.bias0 : (chunk == 1) ? p.bias1
                              : (chunk == 2) ? p.bias2 : p.bias3;
          u16* dst = (chunk == 0) ? p.ob0 : (chunk == 1) ? p.ob1
                     : (chunk == 2) ? p.ob2 : p.ob3;
          v += bias[nl];
          if (chunk == 3) v = 1.f / (1.f + __expf(-v));
          dst[(size_t)row * 1024 + nl] = f2b(v);
        } else if (EPI == GE_OPROJ) {
          v += p.bias0[col];
          const size_t idx = (size_t)row * 1024 + col;
          p.outF[idx] = p.resF[idx] + b2f(p.gate[idx]) * v;
        } else {
          v += p.bias0[col];
          const size_t idx = (size_t)row * 1024 + col;
          const float u = p.resF[idx];
          const float h = (u - p.mean[row]) * p.rstd[row] * p.lnS[col] + p.lnB[col];
          p.outF[idx] = h + v;
        }
      }
    }
  }
}

// ---------- fused attention per (local b, h) ----------
__global__ __launch_bounds__(256, 2) void attn_kernel(
    const u16* __restrict__ QB, const u16* __restrict__ KB,
    const u16* __restrict__ VB, const float* __restrict__ rel,
    u16* __restrict__ AOB, int b_off) {
  __shared__ __align__(16) u16 sK[128 * 128];
  __shared__ __align__(16) u16 sP[128 * 128];
  const int tid = threadIdx.x, w = tid >> 6, l = tid & 63;
  const int bl = blockIdx.x >> 3, h = blockIdx.x & 7;
  const int bg = b_off + bl;
  const size_t base = ((size_t)bl * 128) * 1024 + h * 128;

#pragma unroll
  for (int i = 0; i < 8; i++) {
    const int c = i * 4 + w;
    gld16(&sK[c * 512], KB + base + (size_t)(c * 4 + (l >> 4)) * 1024 + (l & 15) * 8);
  }
  v8s qf[2][4];
#pragma unroll
  for (int mt = 0; mt < 2; mt++)
#pragma unroll
    for (int kb = 0; kb < 4; kb++)
      qf[mt][kb] = *(const v8s*)(QB + base + (size_t)(w * 32 + mt * 16 + (l & 15)) * 1024 +
                                 kb * 32 + (l >> 4) * 8);
  __syncthreads();

  v4f s[2][8];
#pragma unroll
  for (int mt = 0; mt < 2; mt++)
#pragma unroll
    for (int nt = 0; nt < 8; nt++) s[mt][nt] = (v4f){0.f, 0.f, 0.f, 0.f};
#pragma unroll
  for (int kb = 0; kb < 4; kb++) {
    v8s kf[8];
#pragma unroll
    for (int nt = 0; nt < 8; nt++)
      kf[nt] = *(const v8s*)&sK[(nt * 16 + (l & 15)) * 128 + kb * 32 + (l >> 4) * 8];
#pragma unroll
    for (int mt = 0; mt < 2; mt++)
#pragma unroll
      for (int nt = 0; nt < 8; nt++) s[mt][nt] = mfma16(qf[mt][kb], kf[nt], s[mt][nt]);
  }

  const float isc = 0.0883883476483184f;  // 1/sqrt(128)
#pragma unroll
  for (int mt = 0; mt < 2; mt++) {
#pragma unroll
    for (int r = 0; r < 4; r++) {
      const int q = w * 32 + mt * 16 + (l >> 4) * 4 + r;
      const float* br = rel + (size_t)(bg - q + 127) * 128 + (l & 15);
      float vv[8];
      float mx = -1e30f;
#pragma unroll
      for (int nt = 0; nt < 8; nt++) {
        const float t = s[mt][nt][r] * isc + br[nt * 16];
        vv[nt] = t;
        mx = fmaxf(mx, t);
      }
#pragma unroll
      for (int d = 1; d < 16; d <<= 1) mx = fmaxf(mx, __shfl_xor(mx, d));
      float sum = 0.f;
#pragma unroll
      for (int nt = 0; nt < 8; nt++) {
        const float e = __expf(vv[nt] - mx);
        vv[nt] = e;
        sum += e;
      }
#pragma unroll
      for (int d = 1; d < 16; d <<= 1) sum += __shfl_xor(sum, d);
      const float rs = 1.f / sum;
#pragma unroll
      for (int nt = 0; nt < 8; nt++)
        sP[q * 128 + nt * 16 + (l & 15)] = f2b(vv[nt] * rs);
    }
  }
  __syncthreads();

#pragma unroll
  for (int it = 0; it < 8; it++) {
    const int idx = it * 256 + tid;
    const int r = idx >> 4, c0 = (idx & 15) * 8;
    const uint4 u = *(const uint4*)(VB + base + (size_t)r * 1024 + c0);
    u16 tmp[8];
    *(uint4*)tmp = u;
#pragma unroll
    for (int j = 0; j < 8; j++) sK[(c0 + j) * 128 + r] = tmp[j];
  }
  __syncthreads();

  v4f o[2][8];
#pragma unroll
  for (int mt = 0; mt < 2; mt++)
#pragma unroll
    for (int nt = 0; nt < 8; nt++) o[mt][nt] = (v4f){0.f, 0.f, 0.f, 0.f};
#pragma unroll
  for (int kb = 0; kb < 4; kb++) {
    v8s pf[2], vf[8];
#pragma unroll
    for (int mt = 0; mt < 2; mt++)
      pf[mt] = *(const v8s*)&sP[(w * 32 + mt * 16 + (l & 15)) * 128 + kb * 32 + (l >> 4) * 8];
#pragma unroll
    for (int nt = 0; nt < 8; nt++)
      vf[nt] = *(const v8s*)&sK[(nt * 16 + (l & 15)) * 128 + kb * 32 + (l >> 4) * 8];
#pragma unroll
    for (int mt = 0; mt < 2; mt++)
#pragma unroll
      for (int nt = 0; nt < 8; nt++) o[mt][nt] = mfma16(pf[mt], vf[nt], o[mt][nt]);
  }
#pragma unroll
  for (int mt = 0; mt < 2; mt++)
#pragma unroll
    for (int nt = 0; nt < 8; nt++) {
      const int col = nt * 16 + (l & 15);
#pragma unroll
      for (int r = 0; r < 4; r++) {
        const int row = w * 32 + mt * 16 + (l >> 4) * 4 + r;
        AOB[base + (size_t)row * 1024 + col] = f2b(o[mt][nt][r]);
      }
    }
}

// ---------- LayerNorm over D=1024 ----------
template <int MODE>
__global__ __launch_bounds__(256) void ln_kernel(
    const float* __restrict__ U, const float* __restrict__ g,
    const float* __restrict__ be, u16* __restrict__ outB,
    float* __restrict__ meanP, float* __restrict__ rstdP,
    float* __restrict__ X, u16* __restrict__ XB, float survive) {
  const int row = blockIdx.x, tid = threadIdx.x, w = tid >> 6, l = tid & 63;
  const size_t off = (size_t)row * 1024 + tid * 4;
  const float4 v = *(const float4*)(U + off);
  float s = v.x + v.y + v.z + v.w;
  float s2 = v.x * v.x + v.y * v.y + v.z * v.z + v.w * v.w;
#pragma unroll
  for (int d = 1; d < 64; d <<= 1) {
    s += __shfl_xor(s, d);
    s2 += __shfl_xor(s2, d);
  }
  __shared__ float red[8];
  if (l == 0) {
    red[w] = s;
    red[4 + w] = s2;
  }
  __syncthreads();
  s = red[0] + red[1] + red[2] + red[3];
  s2 = red[4] + red[5] + red[6] + red[7];
  const float mean = s * (1.f / 1024.f);
  const float var = s2 * (1.f / 1024.f) - mean * mean;
  const float rstd = rsqrtf(var + 1e-6f);
  const float4 gg = *(const float4*)(g + tid * 4);
  const float4 bb = *(const float4*)(be + tid * 4);
  float o0 = (v.x - mean) * rstd * gg.x + bb.x;
  float o1 = (v.y - mean) * rstd * gg.y + bb.y;
  float o2 = (v.z - mean) * rstd * gg.z + bb.z;
  float o3 = (v.w - mean) * rstd * gg.w + bb.w;
  if (MODE == 1) {
    ushort4 pb = {f2b(o0), f2b(o1), f2b(o2), f2b(o3)};
    *(ushort4*)(outB + off) = pb;
    if (tid == 0) {
      meanP[row] = mean;
      rstdP[row] = rstd;
    }
  } else {
    const float4 xv = *(const float4*)(X + off);
    const float n0 = xv.x + survive * (o0 - xv.x);
    const float n1 = xv.y + survive * (o1 - xv.y);
    const float n2 = xv.z + survive * (o2 - xv.z);
    const float n3 = xv.w + survive * (o3 - xv.w);
    *(float4*)(X + off) = make_float4(n0, n1, n2, n3);
    ushort4 pb = {f2b(n0), f2b(n1), f2b(n2), f2b(n3)};
    *(ushort4*)(XB + off) = pb;
  }
}

// ---------- pooling: 4 blocks per batch, 256 cols each ----------
__global__ __launch_bounds__(256) void pool_kernel(const float* __restrict__ X,
                                                   const float* __restrict__ other,
                                                   float* __restrict__ pooled) {
  const int b = blockIdx.x >> 2, c = blockIdx.x & 3, tid = threadIdx.x;
  const int d = c * 256 + tid;
  float sm = 0.f, mx = -1e30f;
  for (int ll = 0; ll < 128; ll++) {
    const float v = X[((size_t)b * 128 + ll) * 1024 + d];
    sm += v;
    mx = fmaxf(mx, v);
  }
  pooled[b * 2112 + d] = sm * (1.f / 128.f);
  pooled[b * 2112 + 1024 + d] = mx;
  if (c == 0 && tid < 64) pooled[b * 2112 + 2048 + tid] = other[b * 64 + tid];
}

// ---------- head ----------
__global__ __launch_bounds__(128) void head_kernel(
    const float* __restrict__ pooled, const float* __restrict__ Wd1,
    const float* __restrict__ bd1, const float* __restrict__ g3,
    const float* __restrict__ b3, const float* __restrict__ Wd2,
    const float* __restrict__ bd2, const float* __restrict__ Wout,
    const float* __restrict__ bout, float* __restrict__ out) {
  const int b = blockIdx.x, n = threadIdx.x, w = n >> 6, l = n & 63;
  __shared__ float sp[2112];
  __shared__ float sy[128];
  __shared__ float r2[4];
  __shared__ float rr[2];
  for (int i = n; i < 2112; i += 128) sp[i] = pooled[b * 2112 + i];
  __syncthreads();
  float a = bd1[n];
  for (int k = 0; k < 2112; k++) a = fmaf(sp[k], Wd1[k * 128 + n], a);
  a = fmaxf(a, 0.f);
  float s = a, s2 = a * a;
#pragma unroll
  for (int d = 1; d < 64; d <<= 1) {
    s += __shfl_xor(s, d);
    s2 += __shfl_xor(s2, d);
  }
  if (l == 0) {
    r2[w] = s;
    r2[2 + w] = s2;
  }
  __syncthreads();
  s = r2[0] + r2[1];
  s2 = r2[2] + r2[3];
  const float mean = s * (1.f / 128.f);
  const float var = s2 * (1.f / 128.f) - mean * mean;
  const float yn = (a - mean) * rsqrtf(var + 1e-6f) * g3[n] + b3[n];
  sy[n] = yn;
  __syncthreads();
  float a2 = bd2[n];
  for (int k = 0; k < 128; k++) a2 = fmaf(sy[k], Wd2[k * 128 + n], a2);
  a2 = fmaxf(a2, 0.f);
  float t = a2 * Wout[n];
#pragma unroll
  for (int d = 1; d < 64; d <<= 1) t += __shfl_xor(t, d);
  if (l == 0) rr[w] = t;
  __syncthreads();
  if (n == 0) out[b] = rr[0] + rr[1] + bout[0];
}

// ---------- launcher ----------
extern "C" void kernel_launch(void* const* d_in, const int* in_sizes, int n_in,
                              void* d_out, int out_size, void* d_ws,
                              size_t ws_size, hipStream_t stream) {
  (void)in_sizes; (void)n_in; (void)out_size;
  const float* cgm = (const float*)d_in[0];
  const float* other = (const float*)d_in[1];
  const float* W_in = (const float*)d_in[2];
  const float* b_in = (const float*)d_in[3];
  const float* rel = (const float*)d_in[4];
  const float* Wq = (const float*)d_in[5];
  const float* bq = (const float*)d_in[6];
  const float* Wk = (const float*)d_in[7];
  const float* bk = (const float*)d_in[8];
  const float* Wv = (const float*)d_in[9];
  const float* bv = (const float*)d_in[10];
  const float* Wo = (const float*)d_in[11];
  const float* bo = (const float*)d_in[12];
  const float* Wg = (const float*)d_in[13];
  const float* bg = (const float*)d_in[14];
  const float* ln1s = (const float*)d_in[15];
  const float* ln1b = (const float*)d_in[16];
  const float* Wf1 = (const float*)d_in[17];
  const float* bf1 = (const float*)d_in[18];
  const float* Wfg = (const float*)d_in[19];
  const float* bfg = (const float*)d_in[20];
  const float* Wf2 = (const float*)d_in[21];
  const float* bf2 = (const float*)d_in[22];
  const float* ln2s = (const float*)d_in[23];
  const float* ln2b = (const float*)d_in[24];
  const float* Wd1 = (const float*)d_in[25];
  const float* bd1 = (const float*)d_in[26];
  const float* l3s = (const float*)d_in[27];
  const float* l3b = (const float*)d_in[28];
  const float* Wd2 = (const float*)d_in[29];
  const float* bd2 = (const float*)d_in[30];
  const float* Wout = (const float*)d_in[31];
  const float* bout = (const float*)d_in[32];
  float* out = (float*)d_out;

  // ---- adaptive memory plan (R multiple of 256) ----
  const size_t WT_LAYER = 17825792ull;
  const size_t POOLED_B = 1081344ull;
  const size_t PER_ROW = 20488ull;
  int R = 0;
  bool all_mode = true;
  for (int cand = 16384; cand >= 256; cand >>= 1)
    if (2 * WT_LAYER * 2 + POOLED_B + (size_t)cand * PER_ROW <= ws_size) { R = cand; break; }
  if (!R) {
    all_mode = false;
    for (int cand = 16384; cand >= 256; cand >>= 1)
      if (WT_LAYER * 2 + POOLED_B + (size_t)cand * PER_ROW <= ws_size) { R = cand; break; }
  }
  if (!R) return;

  char* p = (char*)d_ws;
  u16* wt = (u16*)p;
  p += (all_mode ? 2 : 1) * WT_LAYER * 2;
  float* pooled = (float*)p; p += POOLED_B;
  float* meanP = (float*)p; p += (size_t)R * 4;
  float* rstdP = (float*)p; p += (size_t)R * 4;
  float* X = (float*)p; p += (size_t)R * 4096;
  u16* XB = (u16*)p; p += (size_t)R * 2048;
  u16* QKVG = (u16*)p; p += (size_t)R * 8192;
  u16* ABH = (u16*)p; p += (size_t)R * 2048;
  float* U = (float*)p; p += (size_t)R * 4096;

  u16* QB = QKVG;
  u16* KB = QKVG + (size_t)R * 1024;
  u16* VB = QKVG + (size_t)R * 2048;
  u16* GB = QKVG + (size_t)R * 3072;
  u16* FB = QKVG;  // [R][4096] alias, lifetime-disjoint
  u16* AOB = ABH;
  u16* HB = ABH;

  const size_t OFF_QKVG = 0, OFF_O = 4194304, OFF_F1 = 5242880,
               OFF_FG = 9437184, OFF_F2 = 13631488;

  auto convert_layer = [&](int i, u16* dst) {
    {
      TransArgs t{};
      t.src[0] = Wq + (size_t)i * 1048576; t.dst[0] = dst + OFF_QKVG;
      t.src[1] = Wk + (size_t)i * 1048576; t.dst[1] = dst + OFF_QKVG + 1048576;
      t.src[2] = Wv + (size_t)i * 1048576; t.dst[2] = dst + OFF_QKVG + 2097152;
      t.src[3] = Wg + (size_t)i * 1048576; t.dst[3] = dst + OFF_QKVG + 3145728;
      t.src[4] = Wo + (size_t)i * 1048576; t.dst[4] = dst + OFF_O;
      t.K = 1024; t.N = 1024;
      wtrans<<<dim3(32, 32, 5), 256, 0, stream>>>(t);
    }
    {
      TransArgs t{};
      t.src[0] = Wf1 + (size_t)i * 4194304; t.dst[0] = dst + OFF_F1;
      t.src[1] = Wfg + (size_t)i * 4194304; t.dst[1] = dst + OFF_FG;
      t.K = 1024; t.N = 4096;
      wtrans<<<dim3(128, 32, 2), 256, 0, stream>>>(t);
    }
    {
      TransArgs t{};
      t.src[0] = Wf2 + (size_t)i * 4194304; t.dst[0] = dst + OFF_F2;
      t.K = 4096; t.N = 1024;
      wtrans<<<dim3(32, 128, 1), 256, 0, stream>>>(t);
    }
  };

  if (all_mode) {
    convert_layer(0, wt);
    convert_layer(1, wt + WT_LAYER);
  }

  const int Bc = R / 128;
  const int nchunks = 16384 / R;

  for (int c = 0; c < nchunks; c++) {
    const int r0 = c * R;
    const int b0 = r0 / 128;

    inproj<<<dim3(8, R / 32), 256, 0, stream>>>(cgm + (size_t)r0 * 32, W_in, b_in, X, XB);

    for (int i = 0; i < 2; i++) {
      u16* W;
      if (all_mode) {
        W = wt + (size_t)i * WT_LAYER;
      } else {
        convert_layer(i, wt);
        W = wt;
      }

      {
        GemmArgs g{};
        g.A = XB; g.Bt = W + OFF_QKVG;
        g.K = 1024; g.N = 4096;
        g.bias0 = bq + i * 1024; g.bias1 = bk + i * 1024;
        g.bias2 = bv + i * 1024; g.bias3 = bg + i * 1024;
        g.ob0 = QB; g.ob1 = KB; g.ob2 = VB; g.ob3 = GB;
        gemm8w<GE_QKVG><<<dim3(16, R / 256), 512, 0, stream>>>(g);
      }
      attn_kernel<<<dim3(Bc * 8), 256, 0, stream>>>(
          QB, KB, VB, rel + (size_t)i * 255 * 128, AOB, b0);
      {
        GemmArgs g{};
        g.A = AOB; g.Bt = W + OFF_O;
        g.K = 1024; g.N = 1024;
        g.bias0 = bo + i * 1024;
        g.resF = X; g.gate = GB; g.outF = U;
        gemm4<128, GE_OPROJ, true><<<dim3(8, R / 128), 256, 0, stream>>>(g);
      }
      ln_kernel<1><<<R, 256, 0, stream>>>(U, ln1s + i * 1024, ln1b + i * 1024,
                                          HB, meanP, rstdP, nullptr, nullptr, 0.f);
      {
        DualArgs dd{};
        dd.A = HB; dd.B1 = W + OFF_F1; dd.B2 = W + OFF_FG;
        dd.bias1 = bf1 + i * 4096; dd.bias2 = bfg + i * 4096;
        dd.out = FB; dd.K = 1024;
        dual8w<<<dim3(32, R / 256), 512, 0, stream>>>(dd);
      }
      {
        GemmArgs g{};
        g.A = FB; g.Bt = W + OFF_F2;
        g.K = 4096; g.N = 1024;
        g.bias0 = bf2 + i * 1024;
        g.resF = U; g.outF = U;
        g.mean = meanP; g.rstd = rstdP;
        g.lnS = ln1s + i * 1024; g.lnB = ln1b + i * 1024;
        gemm4<128, GE_FF2, true><<<dim3(8, R / 128), 256, 0, stream>>>(g);
      }
      const float survive = (i == 0) ? 1.0f : 0.5f;
      ln_kernel<2><<<R, 256, 0, stream>>>(U, ln2s + i * 1024, ln2b + i * 1024,
                                          nullptr, nullptr, nullptr, X, XB, survive);
    }
    pool_kernel<<<Bc * 4, 256, 0, stream>>>(X, other + (size_t)b0 * 64,
                                            pooled + (size_t)b0 * 2112);
  }
  head_kernel<<<128, 128, 0, stream>>>(pooled, Wd1, bd1, l3s, l3b, Wd2, bd2,
                                       Wout, bout, out);
}